// Round 4
// baseline (341.646 us; speedup 1.0000x reference)
//
#include <hip/hip_runtime.h>
#include <stdint.h>

#define N_PTS 1000000
#define B_SEG 64
#define HID 128
#define AFFD 16
#define AH 64
#define AL 32
#define AA 8
#define TPB 128       // threads per block (2 waves)
#define P 4           // points per thread
#define PTS_BLK (TPB * P)  // 512

// Output flat offsets in FLOAT elements (return order: affordances, recon_pos,
// coh_signal, coh_spatial, agent_action, agent_h_next). Output dtype: float32.
#define O_AFF 0
#define O_REC (16 * N_PTS)
#define O_SIG (19 * N_PTS)
#define O_SPA (19 * N_PTS + B_SEG)
#define O_ACT (20 * N_PTS + B_SEG)
#define O_HN  (20 * N_PTS + B_SEG + B_SEG * AA)

// ---------------------------------------------------------------------------
// Kernel 1: per-point MLPs.
// History:
//   R0: P=8, LDS bcast weights, lb(128,2) -> VGPR=128, 204us, occ 13.9% (grid-starved)
//   R1: P=4, lb(128,4)  -> allocator split VGPR/AGPR 64/64, spills, 222us
//   R2: P=4, waves_per_eu(4,4) -> same 64-reg split, 217us
//   R3: P=4, phase-split LDS, lb(128,2) -> CLEAN (VGPR=76) but 233us.
//       Key: VALU issue time constant R0<->R3 (~110us); stall time grew.
//       P=4 doubled waves => doubled broadcast ds_read_b128 count (2.5M->5M);
//       broadcast pays full 64-lane return BW (~12cyc/CU) => LDS pipe ~97us,
//       co-dominant and badly overlapped.
// R4: weights are WAVE-UNIFORM (index j is a loop counter) -> read them from
// global with uniform addresses so the compiler emits s_load into SGPRs.
// One 16B scalar-cache fill replaces a 1024B LDS broadcast return. No LDS,
// no barriers, no staging, no VALU address math. FMAs are v_fma(v,s,v)
// (exactly 1 SGPR operand = legal). P decoupled from the memory system:
// P=4 keeps the clean ~100-VGPR allocation and 3.8 waves/SIMD for latency
// hiding. ws layout: [seg][18] = {err_sum, count, aff_sum[16]}   (fp32)
// ---------------------------------------------------------------------------
__global__ __launch_bounds__(TPB, 2) void point_kernel(
    const float* __restrict__ pos, const int* __restrict__ batch,
    const float* __restrict__ Wf1, const float* __restrict__ bf1v,
    const float* __restrict__ Wf2, const float* __restrict__ bf2v,
    const float* __restrict__ Wg1, const float* __restrict__ bg1v,
    const float* __restrict__ Wg2, const float* __restrict__ bg2v,
    float* __restrict__ out, float* __restrict__ ws) {
  const int tid = threadIdx.x;
  const int base = blockIdx.x * PTS_BLK;

  float px[P], py[P], pz[P];
  int seg[P];
  bool val[P];
#pragma unroll
  for (int i = 0; i < P; i++) {
    int p = base + i * TPB + tid;
    val[i] = (p < N_PTS);
    if (!val[i]) p = N_PTS - 1;  // clamp: uniform control flow in hot loops
    px[i] = pos[p * 3 + 0];
    py[i] = pos[p * 3 + 1];
    pz[i] = pos[p * 3 + 2];
    seg[i] = batch[p];
  }

  // aff init from bf2 (uniform float4 loads -> s_load_dwordx4).
  const float4* bf2q = (const float4*)bf2v;
  const float4 b2a = bf2q[0], b2b = bf2q[1], b2c = bf2q[2], b2d = bf2q[3];
  float aff[P][AFFD];
#pragma unroll
  for (int i = 0; i < P; i++) {
    aff[i][0] = b2a.x;  aff[i][1] = b2a.y;  aff[i][2] = b2a.z;  aff[i][3] = b2a.w;
    aff[i][4] = b2b.x;  aff[i][5] = b2b.y;  aff[i][6] = b2b.z;  aff[i][7] = b2b.w;
    aff[i][8] = b2c.x;  aff[i][9] = b2c.y;  aff[i][10] = b2c.z; aff[i][11] = b2c.w;
    aff[i][12] = b2d.x; aff[i][13] = b2d.y; aff[i][14] = b2d.z; aff[i][15] = b2d.w;
  }

  const float4* Wf2v = (const float4*)Wf2;  // [j][k] contiguous, 16B-aligned

  // F: 3 -> 128 (relu) -> 16.  All weights via uniform (scalar) loads.
#pragma unroll 2
  for (int j = 0; j < HID; j++) {
    const float w0 = Wf1[0 * HID + j];
    const float w1 = Wf1[1 * HID + j];
    const float w2 = Wf1[2 * HID + j];
    const float bb = bf1v[j];
    const float4 r0 = Wf2v[j * 4 + 0];
    const float4 r1 = Wf2v[j * 4 + 1];
    const float4 r2 = Wf2v[j * 4 + 2];
    const float4 r3 = Wf2v[j * 4 + 3];
#pragma unroll
    for (int i = 0; i < P; i++) {
      float h = fmaf(px[i], w0, fmaf(py[i], w1, fmaf(pz[i], w2, bb)));
      h = fmaxf(h, 0.f);
      aff[i][0]  = fmaf(h, r0.x, aff[i][0]);  aff[i][1]  = fmaf(h, r0.y, aff[i][1]);
      aff[i][2]  = fmaf(h, r0.z, aff[i][2]);  aff[i][3]  = fmaf(h, r0.w, aff[i][3]);
      aff[i][4]  = fmaf(h, r1.x, aff[i][4]);  aff[i][5]  = fmaf(h, r1.y, aff[i][5]);
      aff[i][6]  = fmaf(h, r1.z, aff[i][6]);  aff[i][7]  = fmaf(h, r1.w, aff[i][7]);
      aff[i][8]  = fmaf(h, r2.x, aff[i][8]);  aff[i][9]  = fmaf(h, r2.y, aff[i][9]);
      aff[i][10] = fmaf(h, r2.z, aff[i][10]); aff[i][11] = fmaf(h, r2.w, aff[i][11]);
      aff[i][12] = fmaf(h, r3.x, aff[i][12]); aff[i][13] = fmaf(h, r3.y, aff[i][13]);
      aff[i][14] = fmaf(h, r3.z, aff[i][14]); aff[i][15] = fmaf(h, r3.w, aff[i][15]);
    }
  }

  // G: 16 -> 128 (relu) -> 3.  Wg1 column j = Wg1[k*HID+j] (strided uniform
  // scalar dwords; 64B scalar-cache lines reused across 16 consecutive j).
  float rc0[P], rc1[P], rc2[P];
  const float bg20 = bg2v[0], bg21 = bg2v[1], bg22 = bg2v[2];
#pragma unroll
  for (int i = 0; i < P; i++) { rc0[i] = bg20; rc1[i] = bg21; rc2[i] = bg22; }
#pragma unroll 2
  for (int j = 0; j < HID; j++) {
    float wg[AFFD];
#pragma unroll
    for (int k = 0; k < AFFD; k++) wg[k] = Wg1[k * HID + j];
    const float g0 = Wg2[j * 3 + 0];
    const float g1 = Wg2[j * 3 + 1];
    const float g2 = Wg2[j * 3 + 2];
    const float bb = bg1v[j];
#pragma unroll
    for (int i = 0; i < P; i++) {
      float h = bb;
#pragma unroll
      for (int k = 0; k < AFFD; k++) h = fmaf(aff[i][k], wg[k], h);
      h = fmaxf(h, 0.f);
      rc0[i] = fmaf(h, g0, rc0[i]);
      rc1[i] = fmaf(h, g1, rc1[i]);
      rc2[i] = fmaf(h, g2, rc2[i]);
    }
  }

  // Errors + stores.
  float err[P];
#pragma unroll
  for (int i = 0; i < P; i++) {
    const float dx = px[i] - rc0[i], dy = py[i] - rc1[i], dz = pz[i] - rc2[i];
    err[i] = fmaf(dx, dx, fmaf(dy, dy, dz * dz));
    if (val[i]) {
      const int p = base + i * TPB + tid;
      float4* oa = (float4*)(out + O_AFF + (size_t)p * 16);
      oa[0] = make_float4(aff[i][0], aff[i][1], aff[i][2], aff[i][3]);
      oa[1] = make_float4(aff[i][4], aff[i][5], aff[i][6], aff[i][7]);
      oa[2] = make_float4(aff[i][8], aff[i][9], aff[i][10], aff[i][11]);
      oa[3] = make_float4(aff[i][12], aff[i][13], aff[i][14], aff[i][15]);
      float* orc = out + O_REC + (size_t)p * 3;
      orc[0] = rc0[i]; orc[1] = rc1[i]; orc[2] = rc2[i];
      out[O_SPA + p] = err[i];
    }
  }

  // --- segment reduction ---
  // Fast path: this thread's P points all valid & same seg, and seg is
  // wave-uniform (true for nearly all waves: segments average ~15.6k points).
  bool tok = true;
#pragma unroll
  for (int i = 0; i < P; i++) tok = tok && (seg[i] == seg[0]) && val[i];
  const int wseg = __shfl(seg[0], 0);
  const bool fast = __all(tok && (seg[0] == wseg));

  if (fast) {
    float v[18];
    v[0] = 0.f;
#pragma unroll
    for (int i = 0; i < P; i++) v[0] += err[i];
    v[1] = (float)P;
#pragma unroll
    for (int k = 0; k < AFFD; k++) {
      float s = 0.f;
#pragma unroll
      for (int i = 0; i < P; i++) s += aff[i][k];
      v[2 + k] = s;
    }
#pragma unroll
    for (int i = 0; i < 18; i++) {
      float x = v[i];
      x += __shfl_down(x, 32);
      x += __shfl_down(x, 16);
      x += __shfl_down(x, 8);
      x += __shfl_down(x, 4);
      x += __shfl_down(x, 2);
      x += __shfl_down(x, 1);
      v[i] = x;
    }
    if ((tid & 63) == 0) {
#pragma unroll
      for (int i = 0; i < 18; i++) atomicAdd(&ws[wseg * 18 + i], v[i]);
    }
  } else {
    // Slow path: handle each i-slice (64 consecutive points per wave).
#pragma unroll
    for (int i = 0; i < P; i++) {
      float v[18];
      v[0] = val[i] ? err[i] : 0.f;
      v[1] = val[i] ? 1.f : 0.f;
#pragma unroll
      for (int k = 0; k < AFFD; k++) v[2 + k] = val[i] ? aff[i][k] : 0.f;
      const int fi = __shfl(seg[i], 0);
      const bool uni = __all((seg[i] == fi) || !val[i]);
      if (uni) {
#pragma unroll
        for (int q = 0; q < 18; q++) {
          float x = v[q];
          x += __shfl_down(x, 32);
          x += __shfl_down(x, 16);
          x += __shfl_down(x, 8);
          x += __shfl_down(x, 4);
          x += __shfl_down(x, 2);
          x += __shfl_down(x, 1);
          v[q] = x;
        }
        if ((tid & 63) == 0) {
#pragma unroll
          for (int q = 0; q < 18; q++) atomicAdd(&ws[fi * 18 + q], v[q]);
        }
      } else if (val[i]) {
#pragma unroll
        for (int q = 0; q < 18; q++) atomicAdd(&ws[seg[i] * 18 + q], v[q]);
      }
    }
  }
}

// ---------------------------------------------------------------------------
// Kernel 2: one block per segment (64 blocks x 64 threads).
// ---------------------------------------------------------------------------
__global__ __launch_bounds__(64) void agent_kernel(
    const float* __restrict__ ws, const float* __restrict__ agent_h,
    const float* __restrict__ Wx, const float* __restrict__ Wh,
    const float* __restrict__ bx, const float* __restrict__ bh,
    const float* __restrict__ Wlat, const float* __restrict__ blat,
    const float* __restrict__ Wact, const float* __restrict__ bact,
    float* __restrict__ out) {
  const int b = blockIdx.x;   // segment
  const int t = threadIdx.x;  // 0..63
  __shared__ float sAff[AFFD];
  __shared__ float sHn[AH];
  __shared__ float sLat[AL];

  const float cnt = fmaxf(ws[b * 18 + 1], 1.f);
  if (t == 0) out[O_SIG + b] = ws[b * 18 + 0] / cnt;
  if (t < AFFD) sAff[t] = ws[b * 18 + 2 + t] / cnt;
  const float h_prev = agent_h[b * AH + t];
  __syncthreads();

  float pr  = bx[t] + bh[t];
  float pz  = bx[64 + t] + bh[64 + t];
  float pnx = bx[128 + t];
  float pnh = bh[128 + t];
#pragma unroll
  for (int k = 0; k < AFFD; k++) {
    const float a = sAff[k];
    pr  = fmaf(a, Wx[k * 192 + t], pr);
    pz  = fmaf(a, Wx[k * 192 + 64 + t], pz);
    pnx = fmaf(a, Wx[k * 192 + 128 + t], pnx);
  }
#pragma unroll
  for (int k = 0; k < AH; k++) {
    const float h = __shfl(h_prev, k);
    pr  = fmaf(h, Wh[k * 192 + t], pr);
    pz  = fmaf(h, Wh[k * 192 + 64 + t], pz);
    pnh = fmaf(h, Wh[k * 192 + 128 + t], pnh);
  }
  const float r = 1.f / (1.f + expf(-pr));
  const float z = 1.f / (1.f + expf(-pz));
  const float n = tanhf(pnx + r * pnh);
  const float hn = fmaf(1.f - z, n, z * h_prev);
  sHn[t] = hn;
  out[O_HN + b * AH + t] = hn;
  __syncthreads();

  if (t < AL) {
    float acc = blat[t];
#pragma unroll
    for (int k = 0; k < AH; k++) acc = fmaf(sHn[k], Wlat[k * AL + t], acc);
    sLat[t] = tanhf(acc);
  }
  __syncthreads();

  if (t < AA) {
    float acc = bact[t];
#pragma unroll
    for (int k = 0; k < AL; k++) acc = fmaf(sLat[k], Wact[k * AA + t], acc);
    out[O_ACT + b * AA + t] = acc;
  }
}

extern "C" void kernel_launch(void* const* d_in, const int* in_sizes, int n_in,
                              void* d_out, int out_size, void* d_ws, size_t ws_size,
                              hipStream_t stream) {
  const float* pos     = (const float*)d_in[0];
  const int*   batch   = (const int*)d_in[1];
  const float* agent_h = (const float*)d_in[2];
  // d_in[3], d_in[4]: coherence_*_prev — unused by the math.
  const float* Wf1  = (const float*)d_in[5];
  const float* bf1v = (const float*)d_in[6];
  const float* Wf2  = (const float*)d_in[7];
  const float* bf2v = (const float*)d_in[8];
  const float* Wg1  = (const float*)d_in[9];
  const float* bg1v = (const float*)d_in[10];
  const float* Wg2  = (const float*)d_in[11];
  const float* bg2v = (const float*)d_in[12];
  const float* Wx   = (const float*)d_in[13];
  const float* Wh   = (const float*)d_in[14];
  const float* bx   = (const float*)d_in[15];
  const float* bh   = (const float*)d_in[16];
  const float* Wlat = (const float*)d_in[17];
  const float* blat = (const float*)d_in[18];
  const float* Wact = (const float*)d_in[19];
  const float* bact = (const float*)d_in[20];
  float* out = (float*)d_out;
  float* ws = (float*)d_ws;

  // ws is re-poisoned 0xAA before every launch — zero the accumulators.
  hipMemsetAsync(ws, 0, B_SEG * 18 * sizeof(float), stream);

  const int nblk = (N_PTS + PTS_BLK - 1) / PTS_BLK;  // 1954
  point_kernel<<<nblk, TPB, 0, stream>>>(pos, batch, Wf1, bf1v, Wf2, bf2v,
                                         Wg1, bg1v, Wg2, bg2v, out, ws);
  agent_kernel<<<B_SEG, 64, 0, stream>>>(ws, agent_h, Wx, Wh, bx, bh,
                                         Wlat, blat, Wact, bact, out);
}

// Round 6
// 222.423 us; speedup vs baseline: 1.5360x; 1.5360x over previous
//
#include <hip/hip_runtime.h>
#include <stdint.h>

#define N_PTS 1000000
#define B_SEG 64
#define HID 128
#define AFFD 16
#define AH 64
#define AL 32
#define AA 8

#define TPB 256                 // 4 waves per block
#define NT 16                   // 16-point tiles per wave
#define PTS_WAVE (16 * NT)      // 256
#define PTS_BLK (PTS_WAVE * 4)  // 1024

// Output flat offsets in FLOAT elements (return order: affordances, recon_pos,
// coh_signal, coh_spatial, agent_action, agent_h_next). Output dtype: float32.
#define O_AFF 0
#define O_REC (16 * N_PTS)
#define O_SIG (19 * N_PTS)
#define O_SPA (19 * N_PTS + B_SEG)
#define O_ACT (20 * N_PTS + B_SEG)
#define O_HN  (20 * N_PTS + B_SEG + B_SEG * AA)

// ---------------------------------------------------------------------------
// R5/R6: MFMA rewrite of the per-point MLPs (R6 = resubmit of R5 after a
// broker-side "container failed twice" with no kernel diagnostic; full
// re-audit found no OOB / divergent-shuffle / hang hazard).
// History: R0 204us (LDS,P=8), R1/R2 217-222 (occupancy pragmas -> AGPR spill),
// R3 233 (phase-split LDS, clean but 2x LDS broadcasts), R4 247 (scalar s_load
// weights: K$ latency worse). Across ALL fp32 variants VALU-issue time pinned
// at ~110us + 90-140us unhidden weight-fetch latency -> structural ~200us.
// Fix: compute both layers as bf16 MFMA (25 GFLOP -> ~10us of matrix pipe),
// TRANSPOSED (M=feature, N=point) so each layer's C-fragment
// (col=pt=lane&15, row=4q+reg; m89-verified) is lane-identical to the next
// layer's B-fragment (n=pt=lane&15, k=4q+(e&3)+16(e>>2)):
//   j = cb*16+4q+reg == kb*32+4q+(e&3)+16(e>>2)  @ cb=2kb+(e>>2), reg=e&3
// => relu+cvt+repack is PURE in-lane register work. No LDS, no shuffles, no
// per-iteration weight fetch (24 weight A-frags preloaded: 96 VGPR).
// Biases fold into spare K lanes (F1: k=3 input 1.0; G1: k=16 input 1.0;
// spurious Ba[4]=1 on q>0 lanes multiplies zero A rows k=20/24/28: harmless).
// ws layout: [seg][18] = {err_sum, count, aff_sum[16]} (fp32)
// ---------------------------------------------------------------------------

typedef __attribute__((ext_vector_type(8))) short bf16x8;  // 8 bf16, 4 VGPRs
typedef __attribute__((ext_vector_type(4))) float f32x4;   // C/D frag

static __device__ __forceinline__ short f2bf(float f) {
  __bf16 b = (__bf16)f;  // hardware cvt, RNE
  return __builtin_bit_cast(short, b);
}

__global__ __launch_bounds__(TPB, 1) void point_kernel(
    const float* __restrict__ pos, const int* __restrict__ batch,
    const float* __restrict__ Wf1, const float* __restrict__ bf1v,
    const float* __restrict__ Wf2, const float* __restrict__ bf2v,
    const float* __restrict__ Wg1, const float* __restrict__ bg1v,
    const float* __restrict__ Wg2, const float* __restrict__ bg2v,
    float* __restrict__ out, float* __restrict__ ws) {
  const int lane = threadIdx.x & 63;
  const int wid = threadIdx.x >> 6;
  const int m = lane & 15;  // point-in-tile (N) / output row (M) index
  const int q = lane >> 4;  // k-quartet group
  const int wbase = blockIdx.x * PTS_BLK + wid * PTS_WAVE;

  // ---- preload all weight A-fragments (once per wave) ----
  // A-frag element e of lane (m,q) holds A[row=m][k = 4q + (e&3) + 16*(e>>2)].
  bf16x8 Af1[8], Ag1[8], Af2[4], Ag2[4];
#pragma unroll
  for (int jb = 0; jb < 8; jb++) {
    const int j = jb * 16 + m;
    // F1: A = Wf1^T (j x k): k0..2 = Wf1[k][j], k3 = bf1 (bias row), rest 0.
    bf16x8 a = {0, 0, 0, 0, 0, 0, 0, 0};
    if (q == 0) {
      a[0] = f2bf(Wf1[0 * HID + j]);
      a[1] = f2bf(Wf1[1 * HID + j]);
      a[2] = f2bf(Wf1[2 * HID + j]);
      a[3] = f2bf(bf1v[j]);
    }
    Af1[jb] = a;
    // G1: A = Wg1^T (j x a): a = 4q+e (<16); k=16 row (q==0,e==4) = bg1 bias.
    bf16x8 g = {0, 0, 0, 0, 0, 0, 0, 0};
#pragma unroll
    for (int e = 0; e < 4; e++) g[e] = f2bf(Wg1[(4 * q + e) * HID + j]);
    if (q == 0) g[4] = f2bf(bg1v[j]);
    Ag1[jb] = g;
  }
#pragma unroll
  for (int kb = 0; kb < 4; kb++) {
    bf16x8 a2, g2;
#pragma unroll
    for (int e = 0; e < 8; e++) {
      const int j = kb * 32 + 4 * q + (e & 3) + 16 * (e >> 2);
      a2[e] = f2bf(Wf2[j * AFFD + m]);                       // A = Wf2^T (a x j)
      g2[e] = (m < 3) ? f2bf(Wg2[j * 3 + m]) : (short)0;    // A = Wg2^T (r x j)
    }
    Af2[kb] = a2;
    Ag2[kb] = g2;
  }
  const float bf2r0 = bf2v[4 * q + 0], bf2r1 = bf2v[4 * q + 1];
  const float bf2r2 = bf2v[4 * q + 2], bf2r3 = bf2v[4 * q + 3];
  const float bg20 = bg2v[0], bg21 = bg2v[1], bg22 = bg2v[2];
  const short one = (short)0x3F80;  // 1.0 in bf16
  const f32x4 zf = {0.f, 0.f, 0.f, 0.f};

  // segment accumulator (register, flushed on seg change / wave end)
  int cur = -1, cntT = 0;
  float accA0 = 0.f, accA1 = 0.f, accA2 = 0.f, accA3 = 0.f, accE = 0.f;

  auto flush = [&]() {
    float r0 = accA0, r1 = accA1, r2 = accA2, r3 = accA3, re = accE;
#pragma unroll
    for (int msk = 1; msk <= 8; msk <<= 1) {
      r0 += __shfl_xor(r0, msk);
      r1 += __shfl_xor(r1, msk);
      r2 += __shfl_xor(r2, msk);
      r3 += __shfl_xor(r3, msk);
      re += __shfl_xor(re, msk);
    }
    if (m == 0) {
      float* wp = ws + cur * 18;
      atomicAdd(wp + 2 + 4 * q + 0, r0);
      atomicAdd(wp + 2 + 4 * q + 1, r1);
      atomicAdd(wp + 2 + 4 * q + 2, r2);
      atomicAdd(wp + 2 + 4 * q + 3, r3);
      if (q == 0) {
        atomicAdd(wp + 0, re);
        atomicAdd(wp + 1, 16.f * (float)cntT);
      }
    }
    accA0 = accA1 = accA2 = accA3 = accE = 0.f;
    cntT = 0;
  };

#pragma unroll 1
  for (int t = 0; t < NT; t++) {
    const int pt0 = wbase + t * 16;
    const int p = pt0 + m;
    const bool v = (p < N_PTS);
    const int pc = v ? p : (N_PTS - 1);
    const float x = pos[pc * 3 + 0], y = pos[pc * 3 + 1], z = pos[pc * 3 + 2];
    const int sg = batch[pc];

    // B = pos^T: n=pt, k: {x,y,z,1} at k=0..3 (q==0 lanes), else 0.
    bf16x8 Bp = {0, 0, 0, 0, 0, 0, 0, 0};
    if (q == 0) {
      Bp[0] = f2bf(x);
      Bp[1] = f2bf(y);
      Bp[2] = f2bf(z);
      Bp[3] = one;
    }

    // F1: h^T = Wf1^T * pos^T, then in-lane relu+cvt into F2's B-frags.
    bf16x8 Bh[4];
#pragma unroll
    for (int kb = 0; kb < 4; kb++) {
      f32x4 c0 = __builtin_amdgcn_mfma_f32_16x16x32_bf16(Af1[2 * kb + 0], Bp, zf, 0, 0, 0);
      f32x4 c1 = __builtin_amdgcn_mfma_f32_16x16x32_bf16(Af1[2 * kb + 1], Bp, zf, 0, 0, 0);
      bf16x8 b;
      b[0] = f2bf(fmaxf(c0[0], 0.f));
      b[1] = f2bf(fmaxf(c0[1], 0.f));
      b[2] = f2bf(fmaxf(c0[2], 0.f));
      b[3] = f2bf(fmaxf(c0[3], 0.f));
      b[4] = f2bf(fmaxf(c1[0], 0.f));
      b[5] = f2bf(fmaxf(c1[1], 0.f));
      b[6] = f2bf(fmaxf(c1[2], 0.f));
      b[7] = f2bf(fmaxf(c1[3], 0.f));
      Bh[kb] = b;
    }

    // F2: aff^T = Wf2^T * h^T  (accumulate over 4 K-blocks)
    f32x4 Ca = zf;
#pragma unroll
    for (int kb = 0; kb < 4; kb++)
      Ca = __builtin_amdgcn_mfma_f32_16x16x32_bf16(Af2[kb], Bh[kb], Ca, 0, 0, 0);
    const float a0 = Ca[0] + bf2r0, a1 = Ca[1] + bf2r1;
    const float a2 = Ca[2] + bf2r2, a3 = Ca[3] + bf2r3;

    // B for G1: aff^T (k=a at 4q+e), k=16 gets 1.0 (bias row lives in Ag1).
    bf16x8 Ba;
    Ba[0] = f2bf(a0);
    Ba[1] = f2bf(a1);
    Ba[2] = f2bf(a2);
    Ba[3] = f2bf(a3);
    Ba[4] = one;
    Ba[5] = 0;
    Ba[6] = 0;
    Ba[7] = 0;

    // G1: h2^T = Wg1^T * aff^T, in-lane relu+cvt into G2's B-frags.
    bf16x8 Bh2[4];
#pragma unroll
    for (int kb = 0; kb < 4; kb++) {
      f32x4 c0 = __builtin_amdgcn_mfma_f32_16x16x32_bf16(Ag1[2 * kb + 0], Ba, zf, 0, 0, 0);
      f32x4 c1 = __builtin_amdgcn_mfma_f32_16x16x32_bf16(Ag1[2 * kb + 1], Ba, zf, 0, 0, 0);
      bf16x8 b;
      b[0] = f2bf(fmaxf(c0[0], 0.f));
      b[1] = f2bf(fmaxf(c0[1], 0.f));
      b[2] = f2bf(fmaxf(c0[2], 0.f));
      b[3] = f2bf(fmaxf(c0[3], 0.f));
      b[4] = f2bf(fmaxf(c1[0], 0.f));
      b[5] = f2bf(fmaxf(c1[1], 0.f));
      b[6] = f2bf(fmaxf(c1[2], 0.f));
      b[7] = f2bf(fmaxf(c1[3], 0.f));
      Bh2[kb] = b;
    }

    // G2: recon^T = Wg2^T * h2^T (rows 0..2 = x,y,z; live on q==0 lanes).
    f32x4 Cr = zf;
#pragma unroll
    for (int kb = 0; kb < 4; kb++)
      Cr = __builtin_amdgcn_mfma_f32_16x16x32_bf16(Ag2[kb], Bh2[kb], Cr, 0, 0, 0);

    float err = 0.f, rc0 = 0.f, rc1 = 0.f, rc2 = 0.f;
    if (q == 0) {
      rc0 = Cr[0] + bg20;
      rc1 = Cr[1] + bg21;
      rc2 = Cr[2] + bg22;
      const float dx = x - rc0, dy = y - rc1, dz = z - rc2;
      err = fmaf(dx, dx, fmaf(dy, dy, dz * dz));
    }

    if (v) {
      float4 st;
      st.x = a0; st.y = a1; st.z = a2; st.w = a3;
      *(float4*)(out + O_AFF + (size_t)p * 16 + 4 * q) = st;  // wave covers 1KB contiguous
      if (q == 0) {
        float* orc = out + O_REC + (size_t)p * 3;
        orc[0] = rc0; orc[1] = rc1; orc[2] = rc2;
        out[O_SPA + p] = err;
      }
    }

    // --- segment accumulation (batch is sorted; tiles almost always clean) ---
    const int useg = __shfl(sg, 0);
    const bool clean = __all(sg == useg) && (pt0 + 16 <= N_PTS);
    if (clean && useg == cur) {
      accA0 += a0; accA1 += a1; accA2 += a2; accA3 += a3;
      accE += err;  // err==0 on q>0
      cntT++;
    } else {
      if (cntT > 0) flush();
      if (clean) {
        cur = useg;
        accA0 = a0; accA1 = a1; accA2 = a2; accA3 = a3;
        accE = err;
        cntT = 1;
      } else {
        cur = -1;
        if (v) {
          float* wp = ws + sg * 18;
          atomicAdd(wp + 2 + 4 * q + 0, a0);
          atomicAdd(wp + 2 + 4 * q + 1, a1);
          atomicAdd(wp + 2 + 4 * q + 2, a2);
          atomicAdd(wp + 2 + 4 * q + 3, a3);
          if (q == 0) {
            atomicAdd(wp + 0, err);
            atomicAdd(wp + 1, 1.f);
          }
        }
      }
    }
  }
  if (cntT > 0) flush();
}

// ---------------------------------------------------------------------------
// Kernel 2: one block per segment (64 blocks x 64 threads). Unchanged.
// ---------------------------------------------------------------------------
__global__ __launch_bounds__(64) void agent_kernel(
    const float* __restrict__ ws, const float* __restrict__ agent_h,
    const float* __restrict__ Wx, const float* __restrict__ Wh,
    const float* __restrict__ bx, const float* __restrict__ bh,
    const float* __restrict__ Wlat, const float* __restrict__ blat,
    const float* __restrict__ Wact, const float* __restrict__ bact,
    float* __restrict__ out) {
  const int b = blockIdx.x;   // segment
  const int t = threadIdx.x;  // 0..63
  __shared__ float sAff[AFFD];
  __shared__ float sHn[AH];
  __shared__ float sLat[AL];

  const float cnt = fmaxf(ws[b * 18 + 1], 1.f);
  if (t == 0) out[O_SIG + b] = ws[b * 18 + 0] / cnt;
  if (t < AFFD) sAff[t] = ws[b * 18 + 2 + t] / cnt;
  const float h_prev = agent_h[b * AH + t];
  __syncthreads();

  float pr  = bx[t] + bh[t];
  float pz  = bx[64 + t] + bh[64 + t];
  float pnx = bx[128 + t];
  float pnh = bh[128 + t];
#pragma unroll
  for (int k = 0; k < AFFD; k++) {
    const float a = sAff[k];
    pr  = fmaf(a, Wx[k * 192 + t], pr);
    pz  = fmaf(a, Wx[k * 192 + 64 + t], pz);
    pnx = fmaf(a, Wx[k * 192 + 128 + t], pnx);
  }
#pragma unroll
  for (int k = 0; k < AH; k++) {
    const float h = __shfl(h_prev, k);
    pr  = fmaf(h, Wh[k * 192 + t], pr);
    pz  = fmaf(h, Wh[k * 192 + 64 + t], pz);
    pnh = fmaf(h, Wh[k * 192 + 128 + t], pnh);
  }
  const float r = 1.f / (1.f + expf(-pr));
  const float z = 1.f / (1.f + expf(-pz));
  const float n = tanhf(pnx + r * pnh);
  const float hn = fmaf(1.f - z, n, z * h_prev);
  sHn[t] = hn;
  out[O_HN + b * AH + t] = hn;
  __syncthreads();

  if (t < AL) {
    float acc = blat[t];
#pragma unroll
    for (int k = 0; k < AH; k++) acc = fmaf(sHn[k], Wlat[k * AL + t], acc);
    sLat[t] = tanhf(acc);
  }
  __syncthreads();

  if (t < AA) {
    float acc = bact[t];
#pragma unroll
    for (int k = 0; k < AL; k++) acc = fmaf(sLat[k], Wact[k * AA + t], acc);
    out[O_ACT + b * AA + t] = acc;
  }
}

extern "C" void kernel_launch(void* const* d_in, const int* in_sizes, int n_in,
                              void* d_out, int out_size, void* d_ws, size_t ws_size,
                              hipStream_t stream) {
  const float* pos     = (const float*)d_in[0];
  const int*   batch   = (const int*)d_in[1];
  const float* agent_h = (const float*)d_in[2];
  // d_in[3], d_in[4]: coherence_*_prev — unused by the math.
  const float* Wf1  = (const float*)d_in[5];
  const float* bf1v = (const float*)d_in[6];
  const float* Wf2  = (const float*)d_in[7];
  const float* bf2v = (const float*)d_in[8];
  const float* Wg1  = (const float*)d_in[9];
  const float* bg1v = (const float*)d_in[10];
  const float* Wg2  = (const float*)d_in[11];
  const float* bg2v = (const float*)d_in[12];
  const float* Wx   = (const float*)d_in[13];
  const float* Wh   = (const float*)d_in[14];
  const float* bx   = (const float*)d_in[15];
  const float* bh   = (const float*)d_in[16];
  const float* Wlat = (const float*)d_in[17];
  const float* blat = (const float*)d_in[18];
  const float* Wact = (const float*)d_in[19];
  const float* bact = (const float*)d_in[20];
  float* out = (float*)d_out;
  float* ws = (float*)d_ws;

  // ws is re-poisoned 0xAA before every launch — zero the accumulators.
  hipMemsetAsync(ws, 0, B_SEG * 18 * sizeof(float), stream);

  const int nblk = (N_PTS + PTS_BLK - 1) / PTS_BLK;  // 977
  point_kernel<<<nblk, TPB, 0, stream>>>(pos, batch, Wf1, bf1v, Wf2, bf2v,
                                         Wg1, bg1v, Wg2, bg2v, out, ws);
  agent_kernel<<<B_SEG, 64, 0, stream>>>(ws, agent_h, Wx, Wh, bx, bh,
                                         Wlat, blat, Wact, bact, out);
}